// Round 14
// baseline (474.158 us; speedup 1.0000x reference)
//
#include <hip/hip_runtime.h>
#include <stdint.h>
#include <stddef.h>

typedef _Float16 f16;
typedef _Float16 half8 __attribute__((ext_vector_type(8)));
typedef _Float16 half4 __attribute__((ext_vector_type(4)));
typedef float floatx4 __attribute__((ext_vector_type(4)));

__device__ __forceinline__ floatx4 mfma16(half8 a, half8 b, floatx4 c) {
    return __builtin_amdgcn_mfma_f32_16x16x32_f16(a, b, c, 0, 0, 0);
}

typedef __attribute__((address_space(3))) void       lds_void_t;
typedef const __attribute__((address_space(1))) void gconst_void_t;

// async 16B/lane global->LDS; lds dest = wave-uniform base + lane*16
__device__ __forceinline__ void async_copy16(void* lds, const void* g) {
    __builtin_amdgcn_global_load_lds((gconst_void_t*)g, (lds_void_t*)lds, 16, 0, 0);
}

// Manual grid barrier (monotonic counter, reset by hipMemsetAsync each launch).
// Release: per-wave VMEM drained by __syncthreads; thread0 agent-fence flushes
// this XCD's L2 before the add. Acquire: spin with agent-scope atomic load,
// then agent-fence invalidates L1/L2 so post-barrier reads see remote writes.
__device__ __forceinline__ void grid_barrier(unsigned* cnt, unsigned target) {
    __syncthreads();
    if (threadIdx.x == 0) {
        __threadfence();
        __hip_atomic_fetch_add(cnt, 1u, __ATOMIC_ACQ_REL, __HIP_MEMORY_SCOPE_AGENT);
        while (__hip_atomic_load(cnt, __ATOMIC_ACQUIRE, __HIP_MEMORY_SCOPE_AGENT) < target)
            __builtin_amdgcn_s_sleep(2);
        __threadfence();
    }
    __syncthreads();
}

// =====================================================================
// R14: ONE persistent kernel (plain launch, graph-capture-safe), 3 manual
// grid barriers. R13's cooperative launch never ran (absmax == max|ref|,
// zeroed output -> launch failed under capture); phase bodies are the
// R12-proven code verbatim. Co-residency by construction: 64KB static LDS
// -> exactly 2 blocks/CU; grid = 512 = 2x256. Block-id maps preserve the
// XCD-confined attn layout (bh = idx&31) and CU pairing (i, i+256 ->
// same bh, groups g and 15-g).
// =====================================================================
__global__ __launch_bounds__(256, 2)
void fused_all(const float* __restrict__ x, const float* __restrict__ w_attn,
               const float* __restrict__ b_attn, const float* __restrict__ w_proj,
               const float* __restrict__ b_proj,
               f16* __restrict__ xh, f16* __restrict__ wattnT,
               f16* __restrict__ wprojT, f16* __restrict__ QKV,
               f16* __restrict__ attn_out, float* __restrict__ y,
               unsigned* __restrict__ bar)
{
    __shared__ __align__(16) unsigned char lds_raw[65536];   // 64KB union

    const int tid  = threadIdx.x;
    const int wave = tid >> 6;
    const int lane = tid & 63;
    const int quad = lane >> 4;
    const int l16  = lane & 15;
    const size_t HSZ = (size_t)32 * 2048 * 64;   // one of Q/K/V regions

    // ================= phase 1: prepass (3072 items, 6/block) =================
    {
        f16* t = (f16*)lds_raw;   // [64][72]
        for (int bid = blockIdx.x; bid < 3072; bid += 512) {
            if (bid < 2048) {      // x f32 -> f16
                const size_t i = ((size_t)bid * 256 + tid) * 8;
                floatx4 a = *(const floatx4*)(x + i);
                floatx4 b = *(const floatx4*)(x + i + 4);
                half8 h;
                h[0]=(f16)a[0]; h[1]=(f16)a[1]; h[2]=(f16)a[2]; h[3]=(f16)a[3];
                h[4]=(f16)b[0]; h[5]=(f16)b[1]; h[6]=(f16)b[2]; h[7]=(f16)b[3];
                *(half8*)(xh + i) = h;
            } else {               // weight transpose via LDS
                const float* W; f16* WT; int Nsz, bx, by;
                if (bid < 2816) {
                    W = w_attn; WT = wattnT; Nsz = 3072;
                    const int r = bid - 2048; by = r / 48; bx = r - by * 48;
                } else {
                    W = w_proj; WT = wprojT; Nsz = 1024;
                    const int r = bid - 2816; by = r >> 4; bx = r & 15;
                }
                const int k0 = by << 6;
                const int n0 = bx << 6;
                {
                    const int r  = tid >> 2;
                    const int c0 = (tid & 3) << 4;
                    #pragma unroll
                    for (int i = 0; i < 4; ++i) {
                        const int c = c0 + (i << 2);
                        floatx4 v = *(const floatx4*)(W + (size_t)(k0 + r) * Nsz + n0 + c);
                        t[(c + 0) * 72 + r] = (f16)v[0];
                        t[(c + 1) * 72 + r] = (f16)v[1];
                        t[(c + 2) * 72 + r] = (f16)v[2];
                        t[(c + 3) * 72 + r] = (f16)v[3];
                    }
                }
                __syncthreads();
                {
                    const int n  = tid >> 2;
                    const int kc = (tid & 3) << 4;
                    #pragma unroll
                    for (int i = 0; i < 2; ++i) {
                        half8 h = *(half8*)&t[n * 72 + kc + (i << 3)];
                        *(half8*)(WT + (size_t)(n0 + n) * 1024 + k0 + kc + (i << 3)) = h;
                    }
                }
                __syncthreads();   // protect t before next iteration's writes
            }
        }
    }
    grid_barrier(bar, 512);

    // ============ phase 2: QKV GEMM (768 tiles, grid-stride) ============
    // R12-proven: BK=64, counted-vmcnt raw-barrier dbuf, XOR chunk-swizzle,
    // R2-coalesced epilogue.
    {
        f16* As = (f16*)lds_raw;                 // [2][128*64]
        f16* Bs = (f16*)(lds_raw + 32768);       // [2][128*64]
        const int Ksz = 1024;
        const int wm  = (wave >> 1) * 64;
        const int wn  = (wave & 1) * 64;
        const int lr  = lane >> 3;
        const int csw = (lane & 7) ^ lr;

        for (int it = blockIdx.x; it < 768; it += 512) {
            const int bx = it % 24;
            const int by = it / 24;
            const int m0 = by * 128;
            const int n0 = bx * 128;

            const f16* AbS = xh     + (size_t)(m0 + wave * 16 + lr) * Ksz + csw * 8;
            const f16* BbS = wattnT + (size_t)(n0 + wave * 16 + lr) * Ksz + csw * 8;

            auto stage = [&](int buf, int kc) {
                f16* AsW = As + buf * 8192 + wave * 16 * 64;
                f16* BsW = Bs + buf * 8192 + wave * 16 * 64;
                #pragma unroll
                for (int h = 0; h < 2; ++h)
                    #pragma unroll
                    for (int c = 0; c < 2; ++c) {
                        const int ro = h * 64 + c * 8;
                        async_copy16(AsW + ro * 64, AbS + (size_t)ro * Ksz + kc);
                        async_copy16(BsW + ro * 64, BbS + (size_t)ro * Ksz + kc);
                    }
            };

            floatx4 acc[4][4] = {};
            stage(0, 0);

            int buf = 0;
            for (int kc = 0; kc < Ksz; kc += 64) {
                if (kc + 64 < Ksz) {
                    stage(buf ^ 1, kc + 64);
                    asm volatile("s_waitcnt vmcnt(8)" ::: "memory");
                } else {
                    asm volatile("s_waitcnt vmcnt(0)" ::: "memory");
                }
                __builtin_amdgcn_sched_barrier(0);
                __builtin_amdgcn_s_barrier();
                __builtin_amdgcn_sched_barrier(0);

                half8 a[2][4], b[2][4];
                #pragma unroll
                for (int kk = 0; kk < 2; ++kk) {
                    #pragma unroll
                    for (int mt = 0; mt < 4; ++mt) {
                        const int row = wm + mt * 16 + l16;
                        a[kk][mt] = *(const half8*)&As[buf * 8192 + row * 64
                                    + ((((kk << 2) + quad) ^ (l16 & 7)) << 3)];
                    }
                    #pragma unroll
                    for (int nt = 0; nt < 4; ++nt) {
                        const int row = wn + nt * 16 + l16;
                        b[kk][nt] = *(const half8*)&Bs[buf * 8192 + row * 64
                                    + ((((kk << 2) + quad) ^ (l16 & 7)) << 3)];
                    }
                }
                asm volatile("s_waitcnt lgkmcnt(0)" ::: "memory");
                __builtin_amdgcn_sched_barrier(0);
                __builtin_amdgcn_s_barrier();

                #pragma unroll
                for (int kk = 0; kk < 2; ++kk)
                    #pragma unroll
                    for (int mt = 0; mt < 4; ++mt)
                        #pragma unroll
                        for (int nt = 0; nt < 4; ++nt)
                            acc[mt][nt] = mfma16(a[kk][mt], b[kk][nt], acc[mt][nt]);
                buf ^= 1;
            }

            #pragma unroll
            for (int mt = 0; mt < 4; ++mt) {
                #pragma unroll
                for (int nt = 0; nt < 4; ++nt) {
                    const int col  = n0 + wn + nt * 16 + l16;
                    const float bv = b_attn[col];
                    const int row0 = m0 + wm + mt * 16 + (quad << 2);
                    const int bb   = row0 >> 11;
                    const int t0   = row0 & 2047;
                    const int hh   = (col >> 6) & 15;
                    const int d    = col & 63;
                    float v0 = acc[mt][nt][0] + bv;
                    float v1 = acc[mt][nt][1] + bv;
                    float v2 = acc[mt][nt][2] + bv;
                    float v3 = acc[mt][nt][3] + bv;
                    if (col < 2048) {   // Q or K: [bh][t][d]
                        f16* dst = QKV + (size_t)(col >> 10) * HSZ
                                 + (((size_t)(bb * 16 + hh) * 2048 + t0) << 6) + d;
                        dst[0]   = (f16)v0;
                        dst[64]  = (f16)v1;
                        dst[128] = (f16)v2;
                        dst[192] = (f16)v3;
                    } else {            // V^T: [bh][d][t]
                        half4 h; h[0]=(f16)v0; h[1]=(f16)v1; h[2]=(f16)v2; h[3]=(f16)v3;
                        *(half4*)(QKV + 2 * HSZ
                                  + (((size_t)(bb * 16 + hh) << 6) + d) * 2048 + t0) = h;
                    }
                }
            }
            __syncthreads();   // LDS safe before next tile's stage
        }
    }
    grid_barrier(bar, 1024);

    // ================= phase 3: attention (R8-proven dual-tile) =================
    {
        f16* Vt  = (f16*)lds_raw;                 // [4][64*64]
        f16* PsB = (f16*)(lds_raw + 32768);       // [4][16*64]
        f16* PsA = (f16*)(lds_raw + 40960);       // [4][16*64]

        const int idx  = blockIdx.x;
        const int bh   = idx & 31;        // fastest -> XCD-confined K/V
        const int yy   = idx >> 5;        // 0..15
        const int g    = (yy < 8) ? yy : 23 - yy;
        const int jA   = 2 * g;
        const int jB   = 2 * g + 1;
        const int head = bh & 15;
        const int b    = bh >> 4;

        const f16* Qh = QKV + ((size_t)bh << 17);
        const f16* Kh = QKV + HSZ + ((size_t)bh << 17);
        const f16* Vh = QKV + 2 * HSZ + ((size_t)bh << 17);

        const int r8 = lane >> 3;
        const int c8 = (lane & 7) ^ r8;
        const f16* vsrcA = Vh + (size_t)(wave * 16 + r8) * 2048 + c8 * 8;
        const f16* vsrcB = vsrcA + (size_t)8 * 2048;

        half8 kf[8], kn[8];
        half8 qA0, qA1, qB0, qB1;
        floatx4 oA[4], oB[4];
        float lpA, lpB;

        auto loadK = [&](int kv0, half8* dst) {
            const f16* kp = Kh + (size_t)(kv0 + l16) * 64 + (quad << 3);
            #pragma unroll
            for (int t = 0; t < 4; ++t) {
                dst[2 * t]     = *(const half8*)(kp + t * 16 * 64);
                dst[2 * t + 1] = *(const half8*)(kp + t * 16 * 64 + 32);
            }
        };
        auto dmaV = [&](int kv0, int buf) {
            async_copy16(Vt + buf * 4096 + wave * 16 * 64,       vsrcA + kv0);
            async_copy16(Vt + buf * 4096 + (wave * 16 + 8) * 64, vsrcB + kv0);
        };

        const int sw = l16 & 7;

        auto compute2 = [&](int kc, bool diagA, half8* kcur) {
            floatx4 sB[4] = {};
            floatx4 sA[4] = {};
            __builtin_amdgcn_s_setprio(1);
            #pragma unroll
            for (int t = 0; t < 4; ++t) {
                sB[t] = mfma16(kcur[2 * t],     qB0, sB[t]);
                sA[t] = mfma16(kcur[2 * t],     qA0, sA[t]);
                sB[t] = mfma16(kcur[2 * t + 1], qB1, sB[t]);
                sA[t] = mfma16(kcur[2 * t + 1], qA1, sA[t]);
            }
            __builtin_amdgcn_s_setprio(0);
            const int qrel = (wave << 4) + l16;
            #pragma unroll
            for (int t = 0; t < 4; ++t) {
                const int c = t * 2 + (quad >> 1);
                const int po = (l16 << 6) + ((c ^ sw) << 3) + ((quad & 1) << 2);
                float b0 = __builtin_amdgcn_exp2f(sB[t][0]);
                float b1 = __builtin_amdgcn_exp2f(sB[t][1]);
                float b2 = __builtin_amdgcn_exp2f(sB[t][2]);
                float b3 = __builtin_amdgcn_exp2f(sB[t][3]);
                lpB += (b0 + b1) + (b2 + b3);
                half4 pkB; pkB[0]=(f16)b0; pkB[1]=(f16)b1; pkB[2]=(f16)b2; pkB[3]=(f16)b3;
                *(half4*)&PsB[(wave << 10) + po] = pkB;
                float a0 = __builtin_amdgcn_exp2f(sA[t][0]);
                float a1 = __builtin_amdgcn_exp2f(sA[t][1]);
                float a2 = __builtin_amdgcn_exp2f(sA[t][2]);
                float a3 = __builtin_amdgcn_exp2f(sA[t][3]);
                if (diagA) {
                    const int kvb = t * 16 + (quad << 2);
                    a0 = (kvb     <= qrel) ? a0 : 0.f;
                    a1 = (kvb + 1 <= qrel) ? a1 : 0.f;
                    a2 = (kvb + 2 <= qrel) ? a2 : 0.f;
                    a3 = (kvb + 3 <= qrel) ? a3 : 0.f;
                }
                lpA += (a0 + a1) + (a2 + a3);
                half4 pkA; pkA[0]=(f16)a0; pkA[1]=(f16)a1; pkA[2]=(f16)a2; pkA[3]=(f16)a3;
                *(half4*)&PsA[(wave << 10) + po] = pkA;
            }
            asm volatile("s_waitcnt lgkmcnt(0)" ::: "memory");
            half8 pB0 = *(const half8*)&PsB[(wave << 10) + (l16 << 6) + (((quad    ) ^ sw) << 3)];
            half8 pB1 = *(const half8*)&PsB[(wave << 10) + (l16 << 6) + (((quad + 4) ^ sw) << 3)];
            half8 pA0 = *(const half8*)&PsA[(wave << 10) + (l16 << 6) + (((quad    ) ^ sw) << 3)];
            half8 pA1 = *(const half8*)&PsA[(wave << 10) + (l16 << 6) + (((quad + 4) ^ sw) << 3)];
            const f16* vbuf = Vt + (kc & 3) * 4096;
            __builtin_amdgcn_s_setprio(1);
            #pragma unroll
            for (int dt = 0; dt < 4; ++dt) {
                const f16* vrow = vbuf + ((dt * 16 + l16) << 6);
                half8 vf0 = *(const half8*)(vrow + (((quad    ) ^ sw) << 3));
                half8 vf1 = *(const half8*)(vrow + (((quad + 4) ^ sw) << 3));
                oB[dt] = mfma16(pB0, vf0, oB[dt]);
                oA[dt] = mfma16(pA0, vf0, oA[dt]);
                oB[dt] = mfma16(pB1, vf1, oB[dt]);
                oA[dt] = mfma16(pA1, vf1, oA[dt]);
            }
            __builtin_amdgcn_s_setprio(0);
        };

        auto compute1 = [&](int kc, half8* kcur) {
            floatx4 s[4] = {};
            __builtin_amdgcn_s_setprio(1);
            #pragma unroll
            for (int t = 0; t < 4; ++t) {
                s[t] = mfma16(kcur[2 * t],     qB0, s[t]);
                s[t] = mfma16(kcur[2 * t + 1], qB1, s[t]);
            }
            __builtin_amdgcn_s_setprio(0);
            const bool diag = (kc == jB);
            const int qrel = (wave << 4) + l16;
            #pragma unroll
            for (int t = 0; t < 4; ++t) {
                float p0 = __builtin_amdgcn_exp2f(s[t][0]);
                float p1 = __builtin_amdgcn_exp2f(s[t][1]);
                float p2 = __builtin_amdgcn_exp2f(s[t][2]);
                float p3 = __builtin_amdgcn_exp2f(s[t][3]);
                if (diag) {
                    const int kvb = t * 16 + (quad << 2);
                    p0 = (kvb     <= qrel) ? p0 : 0.f;
                    p1 = (kvb + 1 <= qrel) ? p1 : 0.f;
                    p2 = (kvb + 2 <= qrel) ? p2 : 0.f;
                    p3 = (kvb + 3 <= qrel) ? p3 : 0.f;
                }
                lpB += (p0 + p1) + (p2 + p3);
                half4 pk; pk[0]=(f16)p0; pk[1]=(f16)p1; pk[2]=(f16)p2; pk[3]=(f16)p3;
                const int c = t * 2 + (quad >> 1);
                *(half4*)&PsB[(wave << 10) + (l16 << 6) + ((c ^ sw) << 3) + ((quad & 1) << 2)] = pk;
            }
            asm volatile("s_waitcnt lgkmcnt(0)" ::: "memory");
            half8 pf0 = *(const half8*)&PsB[(wave << 10) + (l16 << 6) + (((quad    ) ^ sw) << 3)];
            half8 pf1 = *(const half8*)&PsB[(wave << 10) + (l16 << 6) + (((quad + 4) ^ sw) << 3)];
            const f16* vbuf = Vt + (kc & 3) * 4096;
            __builtin_amdgcn_s_setprio(1);
            #pragma unroll
            for (int dt = 0; dt < 4; ++dt) {
                const f16* vrow = vbuf + ((dt * 16 + l16) << 6);
                half8 vf0 = *(const half8*)(vrow + (((quad    ) ^ sw) << 3));
                half8 vf1 = *(const half8*)(vrow + (((quad + 4) ^ sw) << 3));
                oB[dt] = mfma16(pf0, vf0, oB[dt]);
                oB[dt] = mfma16(pf1, vf1, oB[dt]);
            }
            __builtin_amdgcn_s_setprio(0);
        };

        const f16 qs = (f16)0.1803368801f;   // (1/8) * log2(e)
        auto loadQ = [&](int j, half8& q0, half8& q1) {
            const f16* qp = Qh + (size_t)(j * 64 + wave * 16 + l16) * 64 + (quad << 3);
            q0 = *(const half8*)qp;
            q1 = *(const half8*)(qp + 32);
            #pragma unroll
            for (int i = 0; i < 8; ++i) { q0[i] *= qs; q1[i] *= qs; }
        };

        loadQ(jA, qA0, qA1);
        loadQ(jB, qB0, qB1);
        oA[0]=oA[1]=oA[2]=oA[3] = (floatx4){0.f,0.f,0.f,0.f};
        oB[0]=oB[1]=oB[2]=oB[3] = (floatx4){0.f,0.f,0.f,0.f};
        lpA = 0.f; lpB = 0.f;

        const int nB = jB + 1;   // even
        loadK(0, kf);
        dmaV(0, 0);
        dmaV(64, 1);

        for (int kc = 0; kc < nB; kc += 2) {
            __syncthreads();
            if (kc + 2 < nB) dmaV((kc + 2) << 6, (kc + 2) & 3);
            if (kc + 3 < nB) dmaV((kc + 3) << 6, (kc + 3) & 3);
            if (kc + 1 < nB) loadK((kc + 1) << 6, kn);
            compute2(kc, kc == jA, kf);
            if (kc + 1 < nB) {
                if (kc + 2 < nB) loadK((kc + 2) << 6, kf);
                if (kc + 1 <= jA) compute2(kc + 1, false, kn);
                else               compute1(kc + 1, kn);
            }
        }

        auto writeO = [&](int j, floatx4* o, float lp) {
            float l = lp;
            l += __shfl_xor(l, 16);
            l += __shfl_xor(l, 32);
            const float inv = 1.f / l;
            const int qrow0 = j * 64 + wave * 16;
            #pragma unroll
            for (int r = 0; r < 4; ++r) {
                const float invr = __shfl(inv, (quad << 2) + r);
                const int row = (b << 11) + qrow0 + (quad << 2) + r;
                f16* op = attn_out + (size_t)row * 1024 + head * 64 + l16;
                #pragma unroll
                for (int dt = 0; dt < 4; ++dt)
                    op[dt * 16] = (f16)(o[dt][r] * invr);
            }
        };
        writeO(jB, oB, lpB);
        writeO(jA, oA, lpA);
        __syncthreads();   // all Vt/Ps reads done before phase 4 reuses LDS
    }
    grid_barrier(bar, 1536);

    // ================= phase 4: proj GEMM (512 tiles, 1/block) =================
    {
        f16* As = (f16*)lds_raw;                 // [2][128*64]
        f16* Bs = (f16*)(lds_raw + 32768);       // [2][64*64]
        const int Ksz = 1024;
        const int wm  = (wave >> 1) * 64;
        const int wn  = (wave & 1) * 32;
        const int bx  = blockIdx.x & 15;   // 16 n-tiles
        const int by  = blockIdx.x >> 4;   // 32 m-tiles
        const int m0  = by * 128;
        const int n0  = bx * 64;

        const int lr  = lane >> 3;
        const int csw = (lane & 7) ^ lr;

        const f16* AbS = attn_out + (size_t)(m0 + wave * 16 + lr) * Ksz + csw * 8;
        const f16* BbS = wprojT   + (size_t)(n0 + wave * 16 + lr) * Ksz + csw * 8;

        auto stage = [&](int buf, int kc) {
            f16* AsW = As + buf * 8192 + wave * 16 * 64;
            f16* BsW = Bs + buf * 4096 + wave * 16 * 64;
            #pragma unroll
            for (int h = 0; h < 2; ++h)
                #pragma unroll
                for (int c = 0; c < 2; ++c) {
                    const int ro = h * 64 + c * 8;
                    async_copy16(AsW + ro * 64, AbS + (size_t)ro * Ksz + kc);
                }
            #pragma unroll
            for (int c = 0; c < 2; ++c) {
                const int ro = c * 8;
                async_copy16(BsW + ro * 64, BbS + (size_t)ro * Ksz + kc);
            }
        };

        floatx4 acc[4][2] = {};
        stage(0, 0);

        int buf = 0;
        for (int kc = 0; kc < Ksz; kc += 64) {
            if (kc + 64 < Ksz) {
                stage(buf ^ 1, kc + 64);
                asm volatile("s_waitcnt vmcnt(6)" ::: "memory");
            } else {
                asm volatile("s_waitcnt vmcnt(0)" ::: "memory");
            }
            __builtin_amdgcn_sched_barrier(0);
            __builtin_amdgcn_s_barrier();
            __builtin_amdgcn_sched_barrier(0);

            half8 a[2][4], b[2][2];
            #pragma unroll
            for (int kk = 0; kk < 2; ++kk) {
                #pragma unroll
                for (int mt = 0; mt < 4; ++mt) {
                    const int row = wm + mt * 16 + l16;
                    a[kk][mt] = *(const half8*)&As[buf * 8192 + row * 64
                                + ((((kk << 2) + quad) ^ (l16 & 7)) << 3)];
                }
                #pragma unroll
                for (int nt = 0; nt < 2; ++nt) {
                    const int row = wn + nt * 16 + l16;
                    b[kk][nt] = *(const half8*)&Bs[buf * 4096 + row * 64
                                + ((((kk << 2) + quad) ^ (l16 & 7)) << 3)];
                }
            }
            asm volatile("s_waitcnt lgkmcnt(0)" ::: "memory");
            __builtin_amdgcn_sched_barrier(0);
            __builtin_amdgcn_s_barrier();

            #pragma unroll
            for (int kk = 0; kk < 2; ++kk)
                #pragma unroll
                for (int mt = 0; mt < 4; ++mt)
                    #pragma unroll
                    for (int nt = 0; nt < 2; ++nt)
                        acc[mt][nt] = mfma16(a[kk][mt], b[kk][nt], acc[mt][nt]);
            buf ^= 1;
        }

        #pragma unroll
        for (int mt = 0; mt < 4; ++mt) {
            #pragma unroll
            for (int nt = 0; nt < 2; ++nt) {
                const int col  = n0 + wn + nt * 16 + l16;
                const float bv = b_proj[col];
                #pragma unroll
                for (int r = 0; r < 4; ++r) {
                    const int row = m0 + wm + mt * 16 + (quad << 2) + r;
                    y[(size_t)row * 1024 + col] = acc[mt][nt][r] + bv;
                }
            }
        }
    }
}

extern "C" void kernel_launch(void* const* d_in, const int* in_sizes, int n_in,
                              void* d_out, int out_size, void* d_ws, size_t ws_size,
                              hipStream_t stream)
{
    const float* x      = (const float*)d_in[0];
    const float* w_attn = (const float*)d_in[1];
    const float* b_attn = (const float*)d_in[2];
    const float* w_proj = (const float*)d_in[3];
    const float* b_proj = (const float*)d_in[4];
    float* y = (float*)d_out;

    f16* xh       = (f16*)d_ws;                         // [4096,1024]
    f16* wattnT   = xh + (size_t)4096 * 1024;           // [3072,1024]
    f16* wprojT   = wattnT + (size_t)3072 * 1024;       // [1024,1024]
    f16* qkv      = wprojT + (size_t)1024 * 1024;       // Q,K: [32][2048][64]; V: [32][64][2048]
    f16* attn_out = qkv + (size_t)3 * 32 * 2048 * 64;   // [4096,1024]
    unsigned* bar = (unsigned*)(attn_out + (size_t)4096 * 1024);

    hipMemsetAsync((void*)bar, 0, 64, stream);          // reset barrier each launch
    fused_all<<<dim3(512), dim3(256), 0, stream>>>(
        x, w_attn, b_attn, w_proj, b_proj,
        xh, wattnT, wprojT, qkv, attn_out, y, bar);
}

// Round 16
// 188.011 us; speedup vs baseline: 2.5220x; 2.5220x over previous
//
#include <hip/hip_runtime.h>
#include <stdint.h>
#include <stddef.h>

typedef _Float16 f16;
typedef _Float16 half8 __attribute__((ext_vector_type(8)));
typedef _Float16 half4 __attribute__((ext_vector_type(4)));
typedef float floatx4 __attribute__((ext_vector_type(4)));

__device__ __forceinline__ floatx4 mfma16(half8 a, half8 b, floatx4 c) {
    return __builtin_amdgcn_mfma_f32_16x16x32_f16(a, b, c, 0, 0, 0);
}

typedef __attribute__((address_space(3))) void       lds_void_t;
typedef const __attribute__((address_space(1))) void gconst_void_t;

// async 16B/lane global->LDS; lds dest = wave-uniform base + lane*16
__device__ __forceinline__ void async_copy16(void* lds, const void* g) {
    __builtin_amdgcn_global_load_lds((gconst_void_t*)g, (lds_void_t*)lds, 16, 0, 0);
}

// ---------------- fused pre-pass ----------------
// blocks [0,2048): convert x f32->f16 row-major
// blocks [2048,2816): transpose w_attn [1024,3072] -> wattnT [3072,1024] f16
// blocks [2816,3072): transpose w_proj [1024,1024] -> wprojT [1024,1024] f16
__global__ __launch_bounds__(256)
void prepass(const float* __restrict__ x, const float* __restrict__ w_attn,
             const float* __restrict__ w_proj,
             f16* __restrict__ xh, f16* __restrict__ wattnT, f16* __restrict__ wprojT)
{
    __shared__ __align__(16) f16 t[64][72];
    const int bid = blockIdx.x;
    if (bid < 2048) {
        const size_t i = ((size_t)bid * 256 + threadIdx.x) * 8;
        floatx4 a = *(const floatx4*)(x + i);
        floatx4 b = *(const floatx4*)(x + i + 4);
        half8 h;
        h[0]=(f16)a[0]; h[1]=(f16)a[1]; h[2]=(f16)a[2]; h[3]=(f16)a[3];
        h[4]=(f16)b[0]; h[5]=(f16)b[1]; h[6]=(f16)b[2]; h[7]=(f16)b[3];
        *(half8*)(xh + i) = h;
        return;
    }
    const float* W; f16* WT; int Nsz, bx, by;
    if (bid < 2816) {
        W = w_attn; WT = wattnT; Nsz = 3072;
        const int r = bid - 2048; by = r / 48; bx = r - by * 48;
    } else {
        W = w_proj; WT = wprojT; Nsz = 1024;
        const int r = bid - 2816; by = r >> 4; bx = r & 15;
    }
    const int k0 = by << 6;
    const int n0 = bx << 6;
    {
        const int r  = threadIdx.x >> 2;
        const int c0 = (threadIdx.x & 3) << 4;
        #pragma unroll
        for (int i = 0; i < 4; ++i) {
            const int c = c0 + (i << 2);
            floatx4 v = *(const floatx4*)(W + (size_t)(k0 + r) * Nsz + n0 + c);
            t[c + 0][r] = (f16)v[0];
            t[c + 1][r] = (f16)v[1];
            t[c + 2][r] = (f16)v[2];
            t[c + 3][r] = (f16)v[3];
        }
    }
    __syncthreads();
    {
        const int n  = threadIdx.x >> 2;
        const int kc = (threadIdx.x & 3) << 4;
        #pragma unroll
        for (int i = 0; i < 2; ++i) {
            half8 h = *(half8*)&t[n][kc + (i << 3)];
            *(half8*)(WT + (size_t)(n0 + n) * 1024 + k0 + kc + (i << 3)) = h;
        }
    }
}

// ---------------- QKV GEMM (R12-proven) ----------------
// BK=64 x counted-vmcnt raw-barrier dbuf; XOR chunk-swizzled LDS (source
// pre-swizzle, linear dest, swizzled reads); R2-coalesced epilogue.
__global__ __launch_bounds__(256, 2)
void gemm_qkv(const f16* __restrict__ A, const f16* __restrict__ BT,
              const float* __restrict__ bias, f16* __restrict__ QKV)
{
    __shared__ __align__(16) f16 As[2][128 * 64];
    __shared__ __align__(16) f16 Bs[2][128 * 64];

    const int tid  = threadIdx.x;
    const int wave = tid >> 6;
    const int lane = tid & 63;
    const int quad = lane >> 4;
    const int l16  = lane & 15;
    const int wm   = (wave >> 1) * 64;
    const int wn   = (wave & 1) * 64;
    const int m0   = blockIdx.y * 128;
    const int n0   = blockIdx.x * 128;
    const int Ksz  = 1024;

    const int lr  = lane >> 3;
    const int csw = (lane & 7) ^ lr;

    const f16* AbS = A  + (size_t)(m0 + wave * 16 + lr) * Ksz + csw * 8;
    const f16* BbS = BT + (size_t)(n0 + wave * 16 + lr) * Ksz + csw * 8;

    auto stage = [&](int buf, int kc) {
        f16* AsW = &As[buf][(wave * 16) * 64];
        f16* BsW = &Bs[buf][(wave * 16) * 64];
        #pragma unroll
        for (int h = 0; h < 2; ++h)
            #pragma unroll
            for (int c = 0; c < 2; ++c) {
                const int ro = h * 64 + c * 8;
                async_copy16(AsW + ro * 64, AbS + (size_t)ro * Ksz + kc);
                async_copy16(BsW + ro * 64, BbS + (size_t)ro * Ksz + kc);
            }
    };

    floatx4 acc[4][4] = {};

    stage(0, 0);

    int buf = 0;
    for (int kc = 0; kc < Ksz; kc += 64) {
        if (kc + 64 < Ksz) {
            stage(buf ^ 1, kc + 64);
            asm volatile("s_waitcnt vmcnt(8)" ::: "memory");
        } else {
            asm volatile("s_waitcnt vmcnt(0)" ::: "memory");
        }
        __builtin_amdgcn_sched_barrier(0);
        __builtin_amdgcn_s_barrier();
        __builtin_amdgcn_sched_barrier(0);

        half8 a[2][4], b[2][4];
        #pragma unroll
        for (int kk = 0; kk < 2; ++kk) {
            #pragma unroll
            for (int mt = 0; mt < 4; ++mt) {
                const int row = wm + mt * 16 + l16;
                a[kk][mt] = *(const half8*)&As[buf][row * 64
                            + ((((kk << 2) + quad) ^ (l16 & 7)) << 3)];
            }
            #pragma unroll
            for (int nt = 0; nt < 4; ++nt) {
                const int row = wn + nt * 16 + l16;
                b[kk][nt] = *(const half8*)&Bs[buf][row * 64
                            + ((((kk << 2) + quad) ^ (l16 & 7)) << 3)];
            }
        }
        asm volatile("s_waitcnt lgkmcnt(0)" ::: "memory");
        __builtin_amdgcn_sched_barrier(0);
        __builtin_amdgcn_s_barrier();

        #pragma unroll
        for (int kk = 0; kk < 2; ++kk)
            #pragma unroll
            for (int mt = 0; mt < 4; ++mt)
                #pragma unroll
                for (int nt = 0; nt < 4; ++nt)
                    acc[mt][nt] = mfma16(a[kk][mt], b[kk][nt], acc[mt][nt]);
        buf ^= 1;
    }

    const size_t HSZ = (size_t)32 * 2048 * 64;
    #pragma unroll
    for (int mt = 0; mt < 4; ++mt) {
        #pragma unroll
        for (int nt = 0; nt < 4; ++nt) {
            const int col  = n0 + wn + nt * 16 + l16;
            const float bv = bias[col];
            const int row0 = m0 + wm + mt * 16 + (quad << 2);
            const int bb   = row0 >> 11;
            const int t0   = row0 & 2047;
            const int hh   = (col >> 6) & 15;
            const int d    = col & 63;
            float v0 = acc[mt][nt][0] + bv;
            float v1 = acc[mt][nt][1] + bv;
            float v2 = acc[mt][nt][2] + bv;
            float v3 = acc[mt][nt][3] + bv;
            if (col < 2048) {   // Q or K: [bh][t][d]
                f16* dst = QKV + (size_t)(col >> 10) * HSZ
                         + (((size_t)(bb * 16 + hh) * 2048 + t0) << 6) + d;
                dst[0]   = (f16)v0;
                dst[64]  = (f16)v1;
                dst[128] = (f16)v2;
                dst[192] = (f16)v3;
            } else {            // V^T: [bh][d][t], 4 consecutive t -> half4
                half4 h; h[0]=(f16)v0; h[1]=(f16)v1; h[2]=(f16)v2; h[3]=(f16)v3;
                *(half4*)(QKV + 2 * HSZ
                          + (((size_t)(bb * 16 + hh) << 6) + d) * 2048 + t0) = h;
            }
        }
    }
}

// ---------------- proj GEMM: 128x64 tile (R12-proven) ----------------
__global__ __launch_bounds__(256, 2)
void gemm_proj(const f16* __restrict__ A, const f16* __restrict__ BT,
               const float* __restrict__ bias, float* __restrict__ C)
{
    __shared__ __align__(16) f16 As[2][128 * 64];
    __shared__ __align__(16) f16 Bs[2][64 * 64];

    const int tid  = threadIdx.x;
    const int wave = tid >> 6;
    const int lane = tid & 63;
    const int quad = lane >> 4;
    const int l16  = lane & 15;
    const int wm   = (wave >> 1) * 64;
    const int wn   = (wave & 1) * 32;
    const int m0   = blockIdx.y * 128;
    const int n0   = blockIdx.x * 64;
    const int Ksz  = 1024;

    const int lr  = lane >> 3;
    const int csw = (lane & 7) ^ lr;

    const f16* AbS = A  + (size_t)(m0 + wave * 16 + lr) * Ksz + csw * 8;
    const f16* BbS = BT + (size_t)(n0 + wave * 16 + lr) * Ksz + csw * 8;

    auto stage = [&](int buf, int kc) {
        f16* AsW = &As[buf][(wave * 16) * 64];
        f16* BsW = &Bs[buf][(wave * 16) * 64];
        #pragma unroll
        for (int h = 0; h < 2; ++h)
            #pragma unroll
            for (int c = 0; c < 2; ++c) {
                const int ro = h * 64 + c * 8;
                async_copy16(AsW + ro * 64, AbS + (size_t)ro * Ksz + kc);
            }
        #pragma unroll
        for (int c = 0; c < 2; ++c) {
            const int ro = c * 8;
            async_copy16(BsW + ro * 64, BbS + (size_t)ro * Ksz + kc);
        }
    };

    floatx4 acc[4][2] = {};

    stage(0, 0);

    int buf = 0;
    for (int kc = 0; kc < Ksz; kc += 64) {
        if (kc + 64 < Ksz) {
            stage(buf ^ 1, kc + 64);
            asm volatile("s_waitcnt vmcnt(6)" ::: "memory");
        } else {
            asm volatile("s_waitcnt vmcnt(0)" ::: "memory");
        }
        __builtin_amdgcn_sched_barrier(0);
        __builtin_amdgcn_s_barrier();
        __builtin_amdgcn_sched_barrier(0);

        half8 a[2][4], b[2][2];
        #pragma unroll
        for (int kk = 0; kk < 2; ++kk) {
            #pragma unroll
            for (int mt = 0; mt < 4; ++mt) {
                const int row = wm + mt * 16 + l16;
                a[kk][mt] = *(const half8*)&As[buf][row * 64
                            + ((((kk << 2) + quad) ^ (l16 & 7)) << 3)];
            }
            #pragma unroll
            for (int nt = 0; nt < 2; ++nt) {
                const int row = wn + nt * 16 + l16;
                b[kk][nt] = *(const half8*)&Bs[buf][row * 64
                            + ((((kk << 2) + quad) ^ (l16 & 7)) << 3)];
            }
        }
        asm volatile("s_waitcnt lgkmcnt(0)" ::: "memory");
        __builtin_amdgcn_sched_barrier(0);
        __builtin_amdgcn_s_barrier();

        #pragma unroll
        for (int kk = 0; kk < 2; ++kk)
            #pragma unroll
            for (int mt = 0; mt < 4; ++mt)
                #pragma unroll
                for (int nt = 0; nt < 2; ++nt)
                    acc[mt][nt] = mfma16(a[kk][mt], b[kk][nt], acc[mt][nt]);
        buf ^= 1;
    }

    #pragma unroll
    for (int mt = 0; mt < 4; ++mt) {
        #pragma unroll
        for (int nt = 0; nt < 2; ++nt) {
            const int col  = n0 + wn + nt * 16 + l16;
            const float bv = bias[col];
            #pragma unroll
            for (int r = 0; r < 4; ++r) {
                const int row = m0 + wm + mt * 16 + (quad << 2) + r;
                C[(size_t)row * 1024 + col] = acc[mt][nt][r] + bv;
            }
        }
    }
}

// ---------------- Flash attention, causal — FUSED DUAL-TILE COMPUTE (R8) ------
__global__ __launch_bounds__(256, 2)
void attn_fwd(const f16* __restrict__ Qb, const f16* __restrict__ Kb,
              const f16* __restrict__ Vb, f16* __restrict__ attn_out)
{
    const int bh   = blockIdx.x;     // 0..31
    const int yy   = blockIdx.y;     // 0..15
    const int g    = (yy < 8) ? yy : 23 - yy;   // CU-pair g with 15-g
    const int jA   = 2 * g;
    const int jB   = 2 * g + 1;
    const int head = bh & 15;
    const int b    = bh >> 4;
    const int tid  = threadIdx.x;
    const int wave = tid >> 6;
    const int lane = tid & 63;
    const int quad = lane >> 4;
    const int l16  = lane & 15;

    __shared__ __align__(16) f16 Vt[4][64 * 64];
    __shared__ __align__(16) f16 PsB[4][16 * 64];
    __shared__ __align__(16) f16 PsA[4][16 * 64];

    const f16* Qh = Qb + ((size_t)bh << 17);
    const f16* Kh = Kb + ((size_t)bh << 17);
    const f16* Vh = Vb + ((size_t)bh << 17);

    const int r8 = lane >> 3;
    const int c8 = (lane & 7) ^ r8;
    const f16* vsrcA = Vh + (size_t)(wave * 16 + r8) * 2048 + c8 * 8;
    const f16* vsrcB = vsrcA + (size_t)8 * 2048;

    half8 kf[8], kn[8];
    half8 qA0, qA1, qB0, qB1;
    floatx4 oA[4], oB[4];
    float lpA, lpB;

    auto loadK = [&](int kv0, half8* dst) {
        const f16* kp = Kh + (size_t)(kv0 + l16) * 64 + (quad << 3);
        #pragma unroll
        for (int t = 0; t < 4; ++t) {
            dst[2 * t]     = *(const half8*)(kp + t * 16 * 64);
            dst[2 * t + 1] = *(const half8*)(kp + t * 16 * 64 + 32);
        }
    };
    auto dmaV = [&](int kv0, int buf) {
        async_copy16(&Vt[buf][(wave * 16) * 64],     vsrcA + kv0);
        async_copy16(&Vt[buf][(wave * 16 + 8) * 64], vsrcB + kv0);
    };

    const int sw = l16 & 7;

    auto compute2 = [&](int kc, bool diagA, half8* kcur) {
        floatx4 sB[4] = {};
        floatx4 sA[4] = {};
        __builtin_amdgcn_s_setprio(1);
        #pragma unroll
        for (int t = 0; t < 4; ++t) {
            sB[t] = mfma16(kcur[2 * t],     qB0, sB[t]);
            sA[t] = mfma16(kcur[2 * t],     qA0, sA[t]);
            sB[t] = mfma16(kcur[2 * t + 1], qB1, sB[t]);
            sA[t] = mfma16(kcur[2 * t + 1], qA1, sA[t]);
        }
        __builtin_amdgcn_s_setprio(0);
        const int qrel = (wave << 4) + l16;
        #pragma unroll
        for (int t = 0; t < 4; ++t) {
            const int c = t * 2 + (quad >> 1);
            const int po = (l16 << 6) + ((c ^ sw) << 3) + ((quad & 1) << 2);
            float b0 = __builtin_amdgcn_exp2f(sB[t][0]);
            float b1 = __builtin_amdgcn_exp2f(sB[t][1]);
            float b2 = __builtin_amdgcn_exp2f(sB[t][2]);
            float b3 = __builtin_amdgcn_exp2f(sB[t][3]);
            lpB += (b0 + b1) + (b2 + b3);
            half4 pkB; pkB[0]=(f16)b0; pkB[1]=(f16)b1; pkB[2]=(f16)b2; pkB[3]=(f16)b3;
            *(half4*)&PsB[wave][po] = pkB;
            float a0 = __builtin_amdgcn_exp2f(sA[t][0]);
            float a1 = __builtin_amdgcn_exp2f(sA[t][1]);
            float a2 = __builtin_amdgcn_exp2f(sA[t][2]);
            float a3 = __builtin_amdgcn_exp2f(sA[t][3]);
            if (diagA) {
                const int kvb = t * 16 + (quad << 2);
                a0 = (kvb     <= qrel) ? a0 : 0.f;
                a1 = (kvb + 1 <= qrel) ? a1 : 0.f;
                a2 = (kvb + 2 <= qrel) ? a2 : 0.f;
                a3 = (kvb + 3 <= qrel) ? a3 : 0.f;
            }
            lpA += (a0 + a1) + (a2 + a3);
            half4 pkA; pkA[0]=(f16)a0; pkA[1]=(f16)a1; pkA[2]=(f16)a2; pkA[3]=(f16)a3;
            *(half4*)&PsA[wave][po] = pkA;
        }
        asm volatile("s_waitcnt lgkmcnt(0)" ::: "memory");
        half8 pB0 = *(const half8*)&PsB[wave][(l16 << 6) + (((quad    ) ^ sw) << 3)];
        half8 pB1 = *(const half8*)&PsB[wave][(l16 << 6) + (((quad + 4) ^ sw) << 3)];
        half8 pA0 = *(const half8*)&PsA[wave][(l16 << 6) + (((quad    ) ^ sw) << 3)];
        half8 pA1 = *(const half8*)&PsA[wave][(l16 << 6) + (((quad + 4) ^ sw) << 3)];
        const f16* vbuf = &Vt[kc & 3][0];
        __builtin_amdgcn_s_setprio(1);
        #pragma unroll
        for (int dt = 0; dt < 4; ++dt) {
            const f16* vrow = vbuf + ((dt * 16 + l16) << 6);
            half8 vf0 = *(const half8*)(vrow + (((quad    ) ^ sw) << 3));
            half8 vf1 = *(const half8*)(vrow + (((quad + 4) ^ sw) << 3));
            oB[dt] = mfma16(pB0, vf0, oB[dt]);
            oA[dt] = mfma16(pA0, vf0, oA[dt]);
            oB[dt] = mfma16(pB1, vf1, oB[dt]);
            oA[dt] = mfma16(pA1, vf1, oA[dt]);
        }
        __builtin_amdgcn_s_setprio(0);
    };

    auto compute1 = [&](int kc, half8* kcur) {
        floatx4 s[4] = {};
        __builtin_amdgcn_s_setprio(1);
        #pragma unroll
        for (int t = 0; t < 4; ++t) {
            s[t] = mfma16(kcur[2 * t],     qB0, s[t]);
            s[t] = mfma16(kcur[2 * t + 1], qB1, s[t]);
        }
        __builtin_amdgcn_s_setprio(0);
        const bool diag = (kc == jB);
        const int qrel = (wave << 4) + l16;
        #pragma unroll
        for (int t = 0; t < 4; ++t) {
            float p0 = __builtin_amdgcn_exp2f(s[t][0]);
            float p1 = __builtin_amdgcn_exp2f(s[t][1]);
            float p2 = __builtin_amdgcn_exp2f(s[t][2]);
            float p3 = __builtin_amdgcn_exp2f(s[t][3]);
            if (diag) {
                const int kvb = t * 16 + (quad << 2);
                p0 = (kvb     <= qrel) ? p0 : 0.f;
                p1 = (kvb + 1 <= qrel) ? p1 : 0.f;
                p2 = (kvb + 2 <= qrel) ? p2 : 0.f;
                p3 = (kvb + 3 <= qrel) ? p3 : 0.f;
            }
            lpB += (p0 + p1) + (p2 + p3);
            half4 pk; pk[0]=(f16)p0; pk[1]=(f16)p1; pk[2]=(f16)p2; pk[3]=(f16)p3;
            const int c = t * 2 + (quad >> 1);
            *(half4*)&PsB[wave][(l16 << 6) + ((c ^ sw) << 3) + ((quad & 1) << 2)] = pk;
        }
        asm volatile("s_waitcnt lgkmcnt(0)" ::: "memory");
        half8 pf0 = *(const half8*)&PsB[wave][(l16 << 6) + (((quad    ) ^ sw) << 3)];
        half8 pf1 = *(const half8*)&PsB[wave][(l16 << 6) + (((quad + 4) ^ sw) << 3)];
        const f16* vbuf = &Vt[kc & 3][0];
        __builtin_amdgcn_s_setprio(1);
        #pragma unroll
        for (int dt = 0; dt < 4; ++dt) {
            const f16* vrow = vbuf + ((dt * 16 + l16) << 6);
            half8 vf0 = *(const half8*)(vrow + (((quad    ) ^ sw) << 3));
            half8 vf1 = *(const half8*)(vrow + (((quad + 4) ^ sw) << 3));
            oB[dt] = mfma16(pf0, vf0, oB[dt]);
            oB[dt] = mfma16(pf1, vf1, oB[dt]);
        }
        __builtin_amdgcn_s_setprio(0);
    };

    const f16 qs = (f16)0.1803368801f;   // (1/8) * log2(e)
    auto loadQ = [&](int j, half8& q0, half8& q1) {
        const f16* qp = Qh + (size_t)(j * 64 + wave * 16 + l16) * 64 + (quad << 3);
        q0 = *(const half8*)qp;
        q1 = *(const half8*)(qp + 32);
        #pragma unroll
        for (int i = 0; i < 8; ++i) { q0[i] *= qs; q1[i] *= qs; }
    };

    loadQ(jA, qA0, qA1);
    loadQ(jB, qB0, qB1);
    oA[0]=oA[1]=oA[2]=oA[3] = (floatx4){0.f,0.f,0.f,0.f};
    oB[0]=oB[1]=oB[2]=oB[3] = (floatx4){0.f,0.f,0.f,0.f};
    lpA = 0.f; lpB = 0.f;

    const int nB = jB + 1;   // even
    loadK(0, kf);
    dmaV(0, 0);
    dmaV(64, 1);

    for (int kc = 0; kc < nB; kc += 2) {
        __syncthreads();
        if (kc + 2 < nB) dmaV((kc + 2) << 6, (kc + 2) & 3);
        if (kc + 3 < nB) dmaV((kc + 3) << 6, (kc + 3) & 3);
        if (kc + 1 < nB) loadK((kc + 1) << 6, kn);
        compute2(kc, kc == jA, kf);
        if (kc + 1 < nB) {
            if (kc + 2 < nB) loadK((kc + 2) << 6, kf);
            if (kc + 1 <= jA) compute2(kc + 1, false, kn);
            else               compute1(kc + 1, kn);
        }
    }

    auto writeO = [&](int j, floatx4* o, float lp) {
        float l = lp;
        l += __shfl_xor(l, 16);
        l += __shfl_xor(l, 32);
        const float inv = 1.f / l;
        const int qrow0 = j * 64 + wave * 16;
        #pragma unroll
        for (int r = 0; r < 4; ++r) {
            const float invr = __shfl(inv, (quad << 2) + r);
            const int row = (b << 11) + qrow0 + (quad << 2) + r;
            f16* op = attn_out + (size_t)row * 1024 + head * 64 + l16;
            #pragma unroll
            for (int dt = 0; dt < 4; ++dt)
                op[dt * 16] = (f16)(o[dt][r] * invr);
        }
    };
    writeO(jB, oB, lpB);
    writeO(jA, oA, lpA);
}

extern "C" void kernel_launch(void* const* d_in, const int* in_sizes, int n_in,
                              void* d_out, int out_size, void* d_ws, size_t ws_size,
                              hipStream_t stream)
{
    const float* x      = (const float*)d_in[0];
    const float* w_attn = (const float*)d_in[1];
    const float* b_attn = (const float*)d_in[2];
    const float* w_proj = (const float*)d_in[3];
    const float* b_proj = (const float*)d_in[4];
    float* y = (float*)d_out;

    f16* xh       = (f16*)d_ws;                         // [4096,1024]
    f16* wattnT   = xh + (size_t)4096 * 1024;           // [3072,1024]
    f16* wprojT   = wattnT + (size_t)3072 * 1024;       // [1024,1024]
    f16* qkv      = wprojT + (size_t)1024 * 1024;       // Q,K: [32][2048][64]; V: [32][64][2048]
    f16* attn_out = qkv + (size_t)3 * 32 * 2048 * 64;   // [4096,1024]

    const size_t HSZ = (size_t)32 * 2048 * 64;

    prepass<<<dim3(3072), dim3(256), 0, stream>>>(x, w_attn, w_proj, xh, wattnT, wprojT);
    gemm_qkv<<<dim3(24, 32), dim3(256), 0, stream>>>(xh, wattnT, b_attn, qkv);
    attn_fwd<<<dim3(32, 16), dim3(256), 0, stream>>>(qkv, qkv + HSZ, qkv + 2 * HSZ, attn_out);
    gemm_proj<<<dim3(16, 32), dim3(256), 0, stream>>>(attn_out, wprojT, b_proj, y);
}